// Round 15
// baseline (436.500 us; speedup 1.0000x reference)
//
#include <hip/hip_runtime.h>
#include <hip/hip_bf16.h>
#include <stdint.h>

typedef __attribute__((ext_vector_type(4))) float f32x4;
typedef __attribute__((ext_vector_type(8))) short s16x8;
typedef unsigned short u16;
typedef unsigned int u32;

#define BM 128
#define BK 64

// round-to-nearest-even f32 -> bf16 (bit pattern)
__device__ __forceinline__ u16 f32_to_bf16(float f) {
    uint32_t u = __float_as_uint(f);
    u = u + 0x7FFFu + ((u >> 16) & 1u);
    return (u16)(u >> 16);
}

__device__ __forceinline__ float bf16_to_f32(u16 h) {
    return __uint_as_float((u32)h << 16);
}

__device__ __forceinline__ void gld_lds16(const void* g, void* l) {
    __builtin_amdgcn_global_load_lds(
        (const __attribute__((address_space(1))) uint32_t*)g,
        (__attribute__((address_space(3))) uint32_t*)l,
        16, 0, 0);
}

// R27 prep: vectorized (G13), R26's OOB fixed. Tile = 32 rows x 64 cols.
// Load: float2/lane, u32(2xbf16) straight store. Transpose: the r-span is
// only 32 -> u32 stores need 16 lanes/column (m = tx&15, rows 2m/2m+1 all
// < 32); half = tx>>4 doubles column coverage. Coverage: c_ = i*16 + ty*2
// + half over i=0..3 hits every column in [0,64) exactly once per (m).
struct PrepOp { const float* in; u16* outB; u16* outT; int R, C, ldoT; };

__global__ void stein_prep(PrepOp p0, PrepOp p1, PrepOp p2, PrepOp p3) {
    const int z = blockIdx.z;
    const PrepOp p = (z == 0) ? p0 : (z == 1) ? p1 : (z == 2) ? p2 : p3;
    const int tx = threadIdx.x, ty = threadIdx.y;     // 32 x 8
    const int c0 = blockIdx.x * 64, r0 = blockIdx.y * 32;
    if (r0 >= p.R) return;                            // rect ops exit early
    __shared__ float tile[32][65];
#pragma unroll
    for (int i = 0; i < 32; i += 8) {
        const size_t off = (size_t)(r0 + ty + i) * p.C + c0 + 2 * tx;
        float2 v = *(const float2*)&p.in[off];
        u32 w = (u32)f32_to_bf16(v.x) | ((u32)f32_to_bf16(v.y) << 16);
        *(u32*)&p.outB[off] = w;
        tile[ty + i][2 * tx] = v.x;
        tile[ty + i][2 * tx + 1] = v.y;
    }
    __syncthreads();
    const int m = tx & 15;            // row-pair: rows 2m, 2m+1 (< 32)
    const int half = tx >> 4;         // column sub-index
#pragma unroll
    for (int i = 0; i < 4; ++i) {
        const int c_ = i * 16 + ty * 2 + half;        // [0, 64)
        u32 w = (u32)f32_to_bf16(tile[2 * m][c_])
              | ((u32)f32_to_bf16(tile[2 * m + 1][c_]) << 16);
        *(u32*)&p.outT[(size_t)(c0 + c_) * p.ldoT + r0 + 2 * m] = w;
    }
}

// Runtime-descriptor GEMM op: C[m,n] = sum_k U[m,k] V[n,k]  (NT, bf16 in).
// R24: Add is bf16 (fp32 R-chain dropped; saves ~100 MB serial traffic).
struct GemmOp {
    const u16* U; const u16* V;
    const u16* Add;                        // bf16 elementwise add (or null)
    u16* OutB; u16* OutT; float* OutF;
    int K, ldu, ldv, N, ldo;
};

// Multi-op kernel: 128x128x64 tile, 512 threads / 8 waves (2M x 4N,
// wave-tile 64x32), 64 KB LDS -> 2 blocks/CU = 16 waves/CU = 4 waves/SIMD.
// Structural model: per CU per K-tile, 192 ds_read_b128 (~2300 cyc) vs 256
// MFMA (~1240 cyc) -> MfmaUtil cap ~35%; measured 31 (89% of cap).
// R26/R27: s_setprio(1) around MFMA bursts — w8 runs 2 independent
// blocks/CU at different phases (m191's role-diversity regime).
// XCD chunking (square ops), OutT LDS bounce, A/B bank swizzle: phys chunk
// p of row r holds logical p ^ (r&7); readers (s*4+(lane>>4)) ^ (lane&7).
__global__ __launch_bounds__(512, 4) void stein_gemm_w8(GemmOp op0, GemmOp op1,
                                                        GemmOp op2, GemmOp op3,
                                                        GemmOp op4) {
    const int z = blockIdx.z;
    const GemmOp op = (z == 0) ? op0 : (z == 1) ? op1 : (z == 2) ? op2
                      : (z == 3) ? op3 : op4;
    int bm = blockIdx.x, bn = blockIdx.y;
    if (op.N >= 2048) {                       // square op: XCD chunking
        const int orig = (int)blockIdx.x + ((int)blockIdx.y << 4);
        const int xcd = orig & 7, idx = orig >> 3;
        bm = (xcd & 3) * 4 + (idx & 3);
        bn = (xcd >> 2) * 8 + (idx >> 2);
    }
    if (bn * 128 >= op.N) return;             // rectangular (N=512) ops

    __shared__ alignas(16) short SMEM[32768];      // 64 KB: Us[2] | Vs[2]
    short* Us0 = SMEM;                             // 2 x BM*BK
    short* Vs0 = SMEM + 2 * BM * BK;               // 2 x 128*BK

    const int t = threadIdx.x;
    const int wave = t >> 6;                  // 0..7
    const int lane = t & 63;
    const int wm = (wave >> 2) * 64;          // 2 M-groups of 64 rows
    const int wn = (wave & 3) * 32;           // 4 N-groups of 32 cols

    // staging: wave w covers A rows [16w,16w+16) and B rows [16w,16w+16);
    // 2 DMA ops each (8 rows x 128 B per op).
    const int lrow8 = lane >> 3;                  // 0..7
    const int lchunk = (lane & 7) ^ lrow8;        // swizzled source chunk
    const u16* gU = op.U + (size_t)(bm * BM + 16 * wave + lrow8) * op.ldu + lchunk * 8;
    const u16* gV = op.V + (size_t)(bn * 128 + 16 * wave + lrow8) * op.ldv + lchunk * 8;
    short* sU = Us0 + (16 * wave) * BK;
    short* sV = Vs0 + (16 * wave) * BK;
    const int bufU = BM * BK;                     // elements per buffer
    const int bufV = 128 * BK;

    f32x4 acc[4][2];
#pragma unroll
    for (int i = 0; i < 4; ++i)
#pragma unroll
        for (int j = 0; j < 2; ++j) acc[i][j] = (f32x4){0.f, 0.f, 0.f, 0.f};

    const int arow = wm + (lane & 15);
    const int brow = wn + (lane & 15);

    // prologue: stage tile 0 into buffer 0
#pragma unroll
    for (int j = 0; j < 2; ++j) {
        gld_lds16(gU + (size_t)(8 * j) * op.ldu, sU + j * 512);
        gld_lds16(gV + (size_t)(8 * j) * op.ldv, sV + j * 512);
    }

    int buf = 0;
    for (int kk = 0; kk < op.K; kk += BK) {
        __syncthreads();   // buffer `buf` staged; prior reads of buf^1 done
        if (kk + BK < op.K) {
            const int kn = kk + BK;
            const int bo = buf ^ 1;
#pragma unroll
            for (int j = 0; j < 2; ++j) {
                gld_lds16(gU + (size_t)(8 * j) * op.ldu + kn, sU + bo * bufU + j * 512);
                gld_lds16(gV + (size_t)(8 * j) * op.ldv + kn, sV + bo * bufV + j * 512);
            }
        }
#pragma unroll
        for (int s = 0; s < 2; ++s) {
            const int cx = (s * 4 + (lane >> 4)) ^ (lane & 7);   // phys chunk
            s16x8 af[4], bfr[2];
#pragma unroll
            for (int i = 0; i < 4; ++i)
                af[i] = ((const s16x8*)(Us0 + (size_t)buf * bufU))[(arow + i * 16) * (BK / 8) + cx];
#pragma unroll
            for (int j = 0; j < 2; ++j)
                bfr[j] = ((const s16x8*)(Vs0 + (size_t)buf * bufV))[(brow + j * 16) * (BK / 8) + cx];
            __builtin_amdgcn_s_setprio(1);
#pragma unroll
            for (int i = 0; i < 4; ++i)
#pragma unroll
                for (int j = 0; j < 2; ++j)
                    acc[i][j] = __builtin_amdgcn_mfma_f32_16x16x32_bf16(
                        af[i], bfr[j], acc[i][j], 0, 0, 0);
            __builtin_amdgcn_s_setprio(0);
        }
        buf ^= 1;
    }

    // ---- epilogue ----  C/D layout: col=lane&15, row=(lane>>4)*4+r
    const int ldo = op.ldo;
    const int ccol = lane & 15;
    const int crow = (lane >> 4) * 4;

    if (op.OutB || op.OutF) {
#pragma unroll
        for (int i = 0; i < 4; ++i) {
#pragma unroll
            for (int j = 0; j < 2; ++j) {
                const int gr0 = bm * BM + wm + i * 16 + crow;
                const int gc = bn * 128 + wn + j * 16 + ccol;
                float v[4];
#pragma unroll
                for (int r = 0; r < 4; ++r) {
                    v[r] = acc[i][j][r];
                    if (op.Add) v[r] += bf16_to_f32(op.Add[(size_t)(gr0 + r) * ldo + gc]);
                }
                if (op.OutB) {
#pragma unroll
                    for (int r = 0; r < 4; ++r)
                        op.OutB[(size_t)(gr0 + r) * ldo + gc] = f32_to_bf16(v[r]);
                }
                if (op.OutF) {
#pragma unroll
                    for (int r = 0; r < 4; ++r)
                        op.OutF[(size_t)(gr0 + r) * ldo + gc] = v[r];
                }
            }
        }
    }

    // transposed bf16 via LDS bounce; T[col][row], stride 132 u16.
    if (op.OutT) {
        __syncthreads();                   // all K-loop LDS reads complete
        u16* T = (u16*)SMEM;               // 128*132*2 = 33792 B <= 64 KB
#pragma unroll
        for (int i = 0; i < 4; ++i) {
#pragma unroll
            for (int j = 0; j < 2; ++j) {
                const int c_ = wn + j * 16 + ccol;
                const int r_ = wm + i * 16 + crow;      // multiple of 4
                uint2 w;
                w.x = (u32)f32_to_bf16(acc[i][j][0]) | ((u32)f32_to_bf16(acc[i][j][1]) << 16);
                w.y = (u32)f32_to_bf16(acc[i][j][2]) | ((u32)f32_to_bf16(acc[i][j][3]) << 16);
                *(uint2*)&T[c_ * 132 + r_] = w;
            }
        }
        __syncthreads();
        const int cpart = t >> 4;          // 0..31: column within pass
        const int m = t & 15;              // 16 B chunk along the row
#pragma unroll
        for (int k2 = 0; k2 < 4; ++k2) {
            const int c_ = k2 * 32 + cpart;
            uint2 x = *(const uint2*)&T[c_ * 132 + m * 8];
            uint2 y = *(const uint2*)&T[c_ * 132 + m * 8 + 4];
            uint4 w; w.x = x.x; w.y = x.y; w.z = y.x; w.w = y.y;
            *(uint4*)&op.OutT[(size_t)(bn * 128 + c_) * ldo + bm * BM + m * 8] = w;
        }
    }
}

// Single-op kernel: 512 threads / 8 waves (4M x 2N, wave-tile 32x32,
// acc[2][2]), BM=128 BN=64, LDS 48 KB -> 512-block grids = 2 blocks/CU =
// 16 waves/CU = 4 waves/SIMD. + setprio around MFMA bursts.
__global__ __launch_bounds__(512, 4) void stein_gemm_sg(GemmOp op0) {
    const GemmOp op = op0;
    int bm = blockIdx.x, bn = blockIdx.y;
    if (op.N >= 1024) {                       // XCD chunking (grid 16x32)
        const int orig = (int)blockIdx.x + ((int)blockIdx.y << 4);
        const int xcd = orig & 7, idx = orig >> 3;
        bm = (xcd & 3) * 4 + (idx & 3);
        bn = (xcd >> 2) * 16 + (idx >> 2);
    }
    if (bn * 64 >= op.N) return;

    __shared__ alignas(16) short SMEM[2 * BM * BK + 2 * 64 * BK];  // 48 KB
    short* Us0 = SMEM;
    short* Vs0 = SMEM + 2 * BM * BK;

    const int t = threadIdx.x;
    const int wave = t >> 6;                  // 0..7
    const int lane = t & 63;
    const int wm = (wave >> 1) * 32;          // 4 M-groups of 32 rows
    const int wn = (wave & 1) * 32;           // 2 N-groups of 32 cols

    // staging: wave w covers A rows [16w,16w+16) (2 ops) and B rows
    // [8w,8w+8) (1 op); 8 rows x 128 B per op.
    const int lrow8 = lane >> 3;
    const int lchunk = (lane & 7) ^ lrow8;
    const u16* gU = op.U + (size_t)(bm * BM + 16 * wave + lrow8) * op.ldu + lchunk * 8;
    const u16* gV = op.V + (size_t)(bn * 64 + 8 * wave + lrow8) * op.ldv + lchunk * 8;
    short* sU = Us0 + (16 * wave) * BK;
    short* sV = Vs0 + (8 * wave) * BK;
    const int bufU = BM * BK;
    const int bufV = 64 * BK;

    f32x4 acc[2][2];
#pragma unroll
    for (int i = 0; i < 2; ++i)
#pragma unroll
        for (int j = 0; j < 2; ++j) acc[i][j] = (f32x4){0.f, 0.f, 0.f, 0.f};

    const int arow = wm + (lane & 15);
    const int brow = wn + (lane & 15);

    // prologue: stage tile 0 into buffer 0
#pragma unroll
    for (int j = 0; j < 2; ++j)
        gld_lds16(gU + (size_t)(8 * j) * op.ldu, sU + j * 512);
    gld_lds16(gV, sV);

    int buf = 0;
    for (int kk = 0; kk < op.K; kk += BK) {
        __syncthreads();
        if (kk + BK < op.K) {
            const int kn = kk + BK;
            const int bo = buf ^ 1;
#pragma unroll
            for (int j = 0; j < 2; ++j)
                gld_lds16(gU + (size_t)(8 * j) * op.ldu + kn, sU + bo * bufU + j * 512);
            gld_lds16(gV + kn, sV + bo * bufV);
        }
#pragma unroll
        for (int s = 0; s < 2; ++s) {
            const int cx = (s * 4 + (lane >> 4)) ^ (lane & 7);
            s16x8 af[2], bfr[2];
#pragma unroll
            for (int i = 0; i < 2; ++i)
                af[i] = ((const s16x8*)(Us0 + (size_t)buf * bufU))[(arow + i * 16) * (BK / 8) + cx];
#pragma unroll
            for (int j = 0; j < 2; ++j)
                bfr[j] = ((const s16x8*)(Vs0 + (size_t)buf * bufV))[(brow + j * 16) * (BK / 8) + cx];
            __builtin_amdgcn_s_setprio(1);
#pragma unroll
            for (int i = 0; i < 2; ++i)
#pragma unroll
                for (int j = 0; j < 2; ++j)
                    acc[i][j] = __builtin_amdgcn_mfma_f32_16x16x32_bf16(
                        af[i], bfr[j], acc[i][j], 0, 0, 0);
            __builtin_amdgcn_s_setprio(0);
        }
        buf ^= 1;
    }

    const int ldo = op.ldo;
    const int ccol = lane & 15;
    const int crow = (lane >> 4) * 4;

#pragma unroll
    for (int i = 0; i < 2; ++i) {
#pragma unroll
        for (int j = 0; j < 2; ++j) {
            const int gr0 = bm * BM + wm + i * 16 + crow;
            const int gc = bn * 64 + wn + j * 16 + ccol;
            float v[4];
#pragma unroll
            for (int r = 0; r < 4; ++r) {
                v[r] = acc[i][j][r];
                if (op.Add) v[r] += bf16_to_f32(op.Add[(size_t)(gr0 + r) * ldo + gc]);
            }
            if (op.OutB) {
#pragma unroll
                for (int r = 0; r < 4; ++r)
                    op.OutB[(size_t)(gr0 + r) * ldo + gc] = f32_to_bf16(v[r]);
            }
            if (op.OutF) {
#pragma unroll
                for (int r = 0; r < 4; ++r)
                    op.OutF[(size_t)(gr0 + r) * ldo + gc] = v[r];
            }
        }
    }
}

static inline GemmOp mkop(const u16* U, const u16* V, int K, int ldu, int ldv,
                          const u16* Add, u16* OutB, u16* OutT, float* OutF,
                          int N = 2048, int ldo = 2048) {
    GemmOp o;
    o.U = U; o.V = V; o.Add = Add; o.OutB = OutB; o.OutT = OutT; o.OutF = OutF;
    o.K = K; o.ldu = ldu; o.ldv = ldv; o.N = N; o.ldo = ldo;
    return o;
}

extern "C" void kernel_launch(void* const* d_in, const int* in_sizes, int n_in,
                              void* d_out, int out_size, void* d_ws, size_t ws_size,
                              hipStream_t stream) {
    const float* A = (const float*)d_in[0];     // (2048, 2048)
    const float* A_F = (const float*)d_in[1];   // (2048, 2048)
    const float* C = (const float*)d_in[2];     // (512, 2048)
    const float* C_F = (const float*)d_in[3];   // (512, 2048)
    const int n = 2048, p = 512;
    (void)in_sizes; (void)n_in; (void)out_size; (void)ws_size;

    char* ws = (char*)d_ws;
    const size_t MB = 1u << 20;
    // ---- Smith squaring, 5 levels -> S_32 (tail bound: see R12 notes).
    // d0b-fold: R_1 = [CFT|W1] [CT|Y]^T in ONE K=1024 GEMM.
    // XT transpose-free via operand swap: (R A)^T = NT(U=A^T, V=R).
    // Asq swapped (U=A^T, V=A) so d1's two z's share the U stream.
    // R24: R carried in bf16 only (Rb); Rup in place Rb = bf16(BX+Rb).
    u16* AT   = (u16*)(ws + 0 * MB);    // A^T  bf16  (A_0 transposed form)
    u16* Ab   = (u16*)(ws + 8 * MB);    // A    bf16  (A_0 row form)
    u16* AFT  = (u16*)(ws + 16 * MB);   // B=A_F^T row bf16 (B_0 row form)
    u16* AFb  = (u16*)(ws + 24 * MB);   // A_F  bf16  (B_0 transposed form)
    u16* WYU  = (u16*)(ws + 32 * MB);   // 2048x1024: [CFT | W1=B C_F^T]
    u16* WYV  = (u16*)(ws + 36 * MB);   // 2048x1024: [CT  | Y=A^T C^T]
    u16* XT   = (u16*)(ws + 32 * MB);   // (R A_i)^T — overlaps WYU/WYV (dead after d0b)
    u16* Rb   = (u16*)(ws + 56 * MB);   // running R bf16 row
    u16* CFb  = (u16*)(ws + 64 * MB);   // C_F bf16 row (level 0 only)
    u16* Cb   = (u16*)(ws + 66 * MB);   // C   bf16 row (level 0 only)
    u16* Tb1  = (u16*)(ws + 68 * MB);   // ping-pong set 1: B_i row
    u16* TbT1 = (u16*)(ws + 76 * MB);   //                  B_i^T
    u16* Ub1  = (u16*)(ws + 84 * MB);   //                  A_i row
    u16* UbT1 = (u16*)(ws + 92 * MB);   //                  A_i^T   (top = 100 MB)

    // fused prep — one launch, z in {A, A_F, C_F, C}; 64-col tiles.
    {
        PrepOp pA  = {A,   Ab,  AT,  n, n, n};
        PrepOp pAF = {A_F, AFb, AFT, n, n, n};
        PrepOp pCF = {C_F, CFb, WYU, p, n, 2 * p};
        PrepOp pC  = {C,   Cb,  WYV, p, n, 2 * p};
        stein_prep<<<dim3(32, 64, 4), dim3(32, 8), 0, stream>>>(pA, pAF, pCF, pC);
    }

    u16* Tb[2]  = {AFT, Tb1};
    u16* TbT[2] = {AFb, TbT1};
    u16* Ub[2]  = {Ab, Ub1};
    u16* UbT[2] = {AT, UbT1};

    dim3 blk8(512);
    dim3 g2(16, 16, 2), g4(16, 16, 4);
    dim3 gs(16, 32, 1);                 // sg kernel single-op grid

    // d0 (z=4): level-0 independent ops.
    {
        GemmOp oW1  = mkop(AFT, CFb, n, n, n, nullptr, WYU + p, nullptr, nullptr, p, 2 * p);
        GemmOp oY   = mkop(AT, Cb, n, n, n, nullptr, WYV + p, nullptr, nullptr, p, 2 * p);
        GemmOp oAsq = mkop(AT, Ab, n, n, n, nullptr, UbT1, Ub1, nullptr);   // swapped
        GemmOp oBsq = mkop(AFT, AFb, n, n, n, nullptr, Tb1, TbT1, nullptr);
        stein_gemm_w8<<<g4, blk8, 0, stream>>>(oW1, oY, oAsq, oBsq, oBsq);
    }
    // d0b: R_1 = [CFT|W1] [CT|Y]^T  (K=1024 concat = RHS + B RHS A)
    {
        GemmOp oR1 = mkop(WYU, WYV, 2 * p, 2 * p, 2 * p, nullptr, Rb, nullptr, nullptr);
        stein_gemm_sg<<<gs, blk8, 0, stream>>>(oR1);
    }

    // levels 1..3: full doubling, stream-sharing pairing.
    // Level 3 drops dead outputs (level 4 needs only UbT[0] and Tb[0]).
    for (int i = 1; i < 4; ++i) {
        const int c = i & 1, nx = c ^ 1;
        // d1: {XT = (R A_i)^T via swap, Asq swapped} — shared U = A_i^T.
        GemmOp oXT = mkop(UbT[c], Rb, n, n, n, nullptr, XT, nullptr, nullptr);
        GemmOp oAsq = mkop(UbT[c], Ub[c], n, n, n, nullptr, UbT[nx],
                           (i == 3) ? nullptr : Ub[nx], nullptr);
        stein_gemm_w8<<<g2, blk8, 0, stream>>>(oXT, oAsq, oAsq, oAsq, oAsq);
        // d2: {Rup = bf16(B_i X + Rb) in place, Bsq} — shared U stream = B_i.
        GemmOp oRup = mkop(Tb[c], XT, n, n, n, Rb, Rb, nullptr, nullptr);
        GemmOp oBsq = mkop(Tb[c], TbT[c], n, n, n, nullptr, Tb[nx],
                           (i == 3) ? nullptr : TbT[nx], nullptr);
        stein_gemm_w8<<<g2, blk8, 0, stream>>>(oRup, oBsq, oBsq, oBsq, oBsq);
    }

    // level 4 (final): S_32 = Rb + B_4 (R_4 A_4) -> d_out. A_4/B_4 in set 0.
    {
        GemmOp oXT = mkop(UbT[0], Rb, n, n, n, nullptr, XT, nullptr, nullptr);
        stein_gemm_sg<<<gs, blk8, 0, stream>>>(oXT);
        GemmOp oFin = mkop(Tb[0], XT, n, n, n, Rb, nullptr, nullptr, (float*)d_out);
        stein_gemm_sg<<<gs, blk8, 0, stream>>>(oFin);
    }
}